// Round 2
// baseline (1438.668 us; speedup 1.0000x reference)
//
#include <hip/hip_runtime.h>

// Fused GRU-vector-neuron cell, MI355X gfx950 — precision-split edition.
// The vn-leaky term inner*K/|K|^2 amplifies K-error by |Q|/|K| (min |K| ~ 0.008
// over 12.8M channels), so the chain r_pre -> r -> delta -> K is computed with
// split-bf16 MFMA (hi/lo pairs, 3 MFMAs per matmul ~ fp32 accuracy). z, Q stay
// plain bf16 (O(1) gain). One block = 16 nodes = 48 rows (row = d*16 + i),
// 512 threads = 8 waves, wave w owns output cols [16w,16w+16).

#define NN   100000
#define CC   128
#define NT   16
#define ROWS 48
#define LSTR 136        // bf16 elems per LDS row: 272B, 16B-aligned
#define RSTR 132        // fp32 elems per r row
#define NBLK (NN / NT)  // 6250 exactly, no tail

typedef unsigned short us;
typedef __bf16 bf16x8 __attribute__((ext_vector_type(8)));
typedef float  f32x4  __attribute__((ext_vector_type(4)));

#define MFMA __builtin_amdgcn_mfma_f32_16x16x32_bf16

__device__ __forceinline__ us f2b(float f) {   // fp32 -> bf16 bits, RNE
    union { float f; unsigned u; } x; x.f = f;
    return (us)((x.u + 0x7FFFu + ((x.u >> 16) & 1u)) >> 16);
}
__device__ __forceinline__ float b2f(us h) {
    union { unsigned u; float f; } x; x.u = ((unsigned)h) << 16;
    return x.f;
}

// ---- weight staging: W[c][o] fp32 -> LDS [o][c] bf16 (hi and/or lo planes) ----
__device__ __forceinline__ void stage_plain(const float* __restrict__ W, us* dst, int tid) {
#pragma unroll
    for (int it = 0; it < 8; ++it) {
        int idx4 = (tid + it * 512) * 4;
        float4 w = *(const float4*)(W + idx4);
        int c = idx4 >> 7, o = idx4 & 127;
        const float* wp = &w.x;
#pragma unroll
        for (int j = 0; j < 4; ++j) dst[(o + j) * LSTR + c] = f2b(wp[j]);
    }
}
__device__ __forceinline__ void stage_split(const float* __restrict__ W, us* dh, us* dl, int tid) {
#pragma unroll
    for (int it = 0; it < 8; ++it) {
        int idx4 = (tid + it * 512) * 4;
        float4 w = *(const float4*)(W + idx4);
        int c = idx4 >> 7, o = idx4 & 127;
        const float* wp = &w.x;
#pragma unroll
        for (int j = 0; j < 4; ++j) {
            float x = wp[j]; us h = f2b(x);
            dh[(o + j) * LSTR + c] = h;
            dl[(o + j) * LSTR + c] = f2b(x - b2f(h));
        }
    }
}
__device__ __forceinline__ void stage_lo(const float* __restrict__ W, us* dl, int tid) {
#pragma unroll
    for (int it = 0; it < 8; ++it) {
        int idx4 = (tid + it * 512) * 4;
        float4 w = *(const float4*)(W + idx4);
        int c = idx4 >> 7, o = idx4 & 127;
        const float* wp = &w.x;
#pragma unroll
        for (int j = 0; j < 4; ++j) {
            float x = wp[j];
            dl[(o + j) * LSTR + c] = f2b(x - b2f(f2b(x)));
        }
    }
}

// ---- matmul passes over the 48-row tile (3 M-fragments) ----
__device__ __forceinline__ void mm3(const us* __restrict__ At, const us* __restrict__ w,
                                    f32x4* acc, int arow, int bo, int kbase) {
#pragma unroll
    for (int kf = 0; kf < 4; ++kf) {
        const int k = kf * 32 + kbase;
        bf16x8 b = *(const bf16x8*)(w + bo * LSTR + k);
#pragma unroll
        for (int m = 0; m < 3; ++m) {
            bf16x8 a = *(const bf16x8*)(At + (m * 16 + arow) * LSTR + k);
            acc[m] = MFMA(a, b, acc[m], 0, 0, 0);
        }
    }
}
// precise: acc += (Ah+Al) @ (Wh+Wl), dropping Al@Wl
__device__ __forceinline__ void mm3s(const us* __restrict__ Ah, const us* __restrict__ Al,
                                     const us* __restrict__ wh, const us* __restrict__ wl,
                                     f32x4* acc, int arow, int bo, int kbase) {
#pragma unroll
    for (int kf = 0; kf < 4; ++kf) {
        const int k = kf * 32 + kbase;
        bf16x8 bh = *(const bf16x8*)(wh + bo * LSTR + k);
        bf16x8 bl = *(const bf16x8*)(wl + bo * LSTR + k);
#pragma unroll
        for (int m = 0; m < 3; ++m) {
            bf16x8 ah = *(const bf16x8*)(Ah + (m * 16 + arow) * LSTR + k);
            bf16x8 al = *(const bf16x8*)(Al + (m * 16 + arow) * LSTR + k);
            acc[m] = MFMA(ah, bh, acc[m], 0, 0, 0);
            acc[m] = MFMA(al, bh, acc[m], 0, 0, 0);
            acc[m] = MFMA(ah, bl, acc[m], 0, 0, 0);
        }
    }
}
// Q = Dh@Wq (plain), K += Dh@Wkh + Dl@Wkh (A-frag reads shared)
__device__ __forceinline__ void mm3_qk(const us* __restrict__ Dh, const us* __restrict__ Dl,
                                       const us* __restrict__ wq, const us* __restrict__ wkh,
                                       f32x4* qacc, f32x4* kacc, int arow, int bo, int kbase) {
#pragma unroll
    for (int kf = 0; kf < 4; ++kf) {
        const int k = kf * 32 + kbase;
        bf16x8 bq = *(const bf16x8*)(wq  + bo * LSTR + k);
        bf16x8 bk = *(const bf16x8*)(wkh + bo * LSTR + k);
#pragma unroll
        for (int m = 0; m < 3; ++m) {
            bf16x8 dh = *(const bf16x8*)(Dh + (m * 16 + arow) * LSTR + k);
            bf16x8 dl = *(const bf16x8*)(Dl + (m * 16 + arow) * LSTR + k);
            qacc[m] = MFMA(dh, bq, qacc[m], 0, 0, 0);
            kacc[m] = MFMA(dh, bk, kacc[m], 0, 0, 0);
            kacc[m] = MFMA(dl, bk, kacc[m], 0, 0, 0);
        }
    }
}

__global__ __launch_bounds__(512, 2) void gru_vn_fused(
    const float* __restrict__ v,   const float* __restrict__ mv,
    const float* __restrict__ Whz, const float* __restrict__ Wiz, const float* __restrict__ bz,
    const float* __restrict__ Whr, const float* __restrict__ Wir, const float* __restrict__ br,
    const float* __restrict__ Whv, const float* __restrict__ Wiv,
    const float* __restrict__ Wq,  const float* __restrict__ Wk,
    float* __restrict__ out)
{
    __shared__ __align__(16) us mvh[ROWS * LSTR], mvl_[ROWS * LSTR];   // m_v, later delta
    __shared__ __align__(16) us vth[ROWS * LSTR], vtl[ROWS * LSTR];    // v
    __shared__ __align__(16) us rvh[ROWS * LSTR], rvl[ROWS * LSTR];    // r*v
    __shared__ __align__(16) us wb0[CC * LSTR], wb1[CC * LSTR];        // weight buffers
    __shared__ __align__(16) float r_t[NT * RSTR];                     // r (fp32)

    const int tid   = threadIdx.x;
    const int lane  = tid & 63;
    const int wave  = tid >> 6;
    const int arow  = lane & 15;
    const int bo    = wave * 16 + arow;
    const int kbase = (lane >> 4) * 8;
    const int rsub  = (lane >> 4) * 4;
    const int n0 = blockIdx.x * NT;

    // ---- stage v, m_v as hi/lo bf16 tile pairs: [d*16 + i][c] ----
    {
        const float* vs = v  + (size_t)n0 * 384;
        const float* ms = mv + (size_t)n0 * 384;
#pragma unroll
        for (int it = 0; it < 3; ++it) {
            int base = tid * 4 + it * 2048;            // 6144 elems exactly
            float4 a = *(const float4*)(vs + base);
            float4 b = *(const float4*)(ms + base);
            const float* ap = &a.x; const float* bp = &b.x;
#pragma unroll
            for (int j = 0; j < 4; ++j) {
                int idx = base + j;
                int i = idx / 384, rem = idx - i * 384;
                int c = rem / 3, d = rem - c * 3;
                int off = (d * NT + i) * LSTR + c;
                float av = ap[j], bv = bp[j];
                us h;
                h = f2b(av); vth[off] = h; vtl[off]  = f2b(av - b2f(h));
                h = f2b(bv); mvh[off] = h; mvl_[off] = f2b(bv - b2f(h));
            }
        }
    }
    stage_plain(Whz, wb0, tid);
    stage_plain(Wiz, wb1, tid);

    const float bzv = bz[bo];
    const float brv = br[bo];
    const f32x4 Z4 = {0.f, 0.f, 0.f, 0.f};
    __syncthreads();                                   // B1

    // ---- z pre-activation (plain) ----
    f32x4 zacc[3] = {Z4, Z4, Z4};
    mm3(mvh, wb0, zacc, arow, bo, kbase);
    mm3(vth, wb1, zacc, arow, bo, kbase);
    __syncthreads();                                   // B2
    stage_split(Whr, wb0, wb1, tid);
    __syncthreads();                                   // B3

    // ---- r pre-activation (precise) ----
    f32x4 racc[3] = {Z4, Z4, Z4};
    mm3s(mvh, mvl_, wb0, wb1, racc, arow, bo, kbase);
    __syncthreads();                                   // B4
    stage_split(Wir, wb0, wb1, tid);
    __syncthreads();                                   // B5
    mm3s(vth, vtl, wb0, wb1, racc, arow, bo, kbase);

    float zz[4];
#pragma unroll
    for (int q = 0; q < 4; ++q) {
        float h0 = zacc[0][q], h1 = zacc[1][q], h2 = zacc[2][q];
        zz[q] = 1.f / (1.f + __expf(-(sqrtf(h0 * h0 + h1 * h1 + h2 * h2) + bzv)));
        float r0 = racc[0][q], r1 = racc[1][q], r2 = racc[2][q];
        float rr = 1.f / (1.f + __expf(-(sqrtf(r0 * r0 + r1 * r1 + r2 * r2) + brv)));
        r_t[(rsub + q) * RSTR + bo] = rr;
    }
    __syncthreads();                                   // B6: r_t visible, wb free

    // ---- build r*v hi/lo tiles; stage Whv ----
#pragma unroll
    for (int it = 0; it < 12; ++it) {
        int e = tid + it * 512;                        // 6144 elems exactly
        int row = e >> 7, c = e & 127, i = row & 15;
        float v32 = b2f(vth[row * LSTR + c]) + b2f(vtl[row * LSTR + c]);
        float p = r_t[i * RSTR + c] * v32;
        us h = f2b(p);
        rvh[row * LSTR + c] = h;
        rvl[row * LSTR + c] = f2b(p - b2f(h));
    }
    stage_split(Whv, wb0, wb1, tid);
    __syncthreads();                                   // B7

    // ---- delta (precise) ----
    f32x4 dacc[3] = {Z4, Z4, Z4};
    mm3s(mvh, mvl_, wb0, wb1, dacc, arow, bo, kbase);
    __syncthreads();                                   // B8
    stage_split(Wiv, wb0, wb1, tid);
    __syncthreads();                                   // B9
    mm3s(rvh, rvl, wb0, wb1, dacc, arow, bo, kbase);

    // write delta hi/lo over dead m_v tiles (no wave reads mv after B8)
#pragma unroll
    for (int m = 0; m < 3; ++m)
#pragma unroll
    for (int q = 0; q < 4; ++q) {
        int row = m * 16 + rsub + q;
        float x = dacc[m][q];
        us h = f2b(x);
        mvh[row * LSTR + bo]  = h;
        mvl_[row * LSTR + bo] = f2b(x - b2f(h));
    }
    __syncthreads();                                   // B10: delta visible, wb free
    stage_plain(Wq, wb0, tid);
    stage_plain(Wk, wb1, tid);                         // = Wk_hi
    __syncthreads();                                   // B11

    // ---- Q (plain), K (precise) ----
    f32x4 qacc[3] = {Z4, Z4, Z4}, kacc[3] = {Z4, Z4, Z4};
    mm3_qk(mvh, mvl_, wb0, wb1, qacc, kacc, arow, bo, kbase);
    __syncthreads();                                   // B12
    stage_lo(Wk, wb0, tid);
    __syncthreads();                                   // B13
    mm3(mvh, wb0, kacc, arow, bo, kbase);              // + delta_hi @ Wk_lo

    // ---- vn-leaky + gate + store ----
#pragma unroll
    for (int q = 0; q < 4; ++q) {
        const int i = rsub + q;
        float q0 = qacc[0][q], q1 = qacc[1][q], q2 = qacc[2][q];
        float k0 = kacc[0][q], k1 = kacc[1][q], k2 = kacc[2][q];
        float inner = fminf(q0 * k0 + q1 * k1 + q2 * k2, 0.f);
        float kn = sqrtf(k0 * k0 + k1 * k1 + k2 * k2) + 1e-7f;
        float s = inner / (kn * kn);
        float z = zz[q];
        float dv0 = 0.3f * dacc[0][q] + 0.7f * (q0 - s * k0);
        float dv1 = 0.3f * dacc[1][q] + 0.7f * (q1 - s * k1);
        float dv2 = 0.3f * dacc[2][q] + 0.7f * (q2 - s * k2);
        float v0 = b2f(vth[(0 * NT + i) * LSTR + bo]) + b2f(vtl[(0 * NT + i) * LSTR + bo]);
        float v1 = b2f(vth[(1 * NT + i) * LSTR + bo]) + b2f(vtl[(1 * NT + i) * LSTR + bo]);
        float v2 = b2f(vth[(2 * NT + i) * LSTR + bo]) + b2f(vtl[(2 * NT + i) * LSTR + bo]);
        float* op = out + ((size_t)(n0 + i) * CC + bo) * 3;
        op[0] = (1.f - z) * v0 + z * dv0;
        op[1] = (1.f - z) * v1 + z * dv1;
        op[2] = (1.f - z) * v2 + z * dv2;
    }
}

extern "C" void kernel_launch(void* const* d_in, const int* in_sizes, int n_in,
                              void* d_out, int out_size, void* d_ws, size_t ws_size,
                              hipStream_t stream) {
    (void)in_sizes; (void)n_in; (void)d_ws; (void)ws_size; (void)out_size;
    gru_vn_fused<<<NBLK, 512, 0, stream>>>(
        (const float*)d_in[0],  (const float*)d_in[1],
        (const float*)d_in[2],  (const float*)d_in[3],  (const float*)d_in[4],
        (const float*)d_in[5],  (const float*)d_in[6],  (const float*)d_in[7],
        (const float*)d_in[8],  (const float*)d_in[9],
        (const float*)d_in[10], (const float*)d_in[11],
        (float*)d_out);
}

// Round 3
// 264.729 us; speedup vs baseline: 5.4345x; 5.4345x over previous
//
#include <hip/hip_runtime.h>

// Fused GRU-vector-neuron cell, MI355X gfx950 — round 3.
// Changes vs round 2 (1438us, 6.7e8 LDS bank conflicts, 23.8% occupancy):
//  * Fragment-major LDS layout: lane-contiguous ds_read_b128 (conflict-free).
//  * Weights pre-converted once per launch (prep kernel) to bf16 hi/lo
//    fragment-major planes in d_ws; main kernel reads B-frags from global
//    (L2-resident) -> no weight LDS, no per-block f2b, 5 barriers not 13.
//  * LDS 56KB -> 2 blocks/CU (16 waves).
// Precision scheme unchanged (passed at absmax 0.031): split-bf16 (hi/lo,
// 3 MFMAs) on the chain r -> delta -> K; plain bf16 for z and Q.

#define NN   100000
#define NT   16
#define NBLK (NN / NT)   // 6250, exact
#define PSZ  16384       // us per weight plane (128x128 bf16)

typedef unsigned short us;
typedef us     us8    __attribute__((ext_vector_type(8)));
typedef __bf16 bf16x8 __attribute__((ext_vector_type(8)));
typedef float  f32x4  __attribute__((ext_vector_type(4)));

#define MFMA __builtin_amdgcn_mfma_f32_16x16x32_bf16

__device__ __forceinline__ us f2b(float f) {   // fp32 -> bf16 bits, RNE
    union { float f; unsigned u; } x; x.f = f;
    return (us)((x.u + 0x7FFFu + ((x.u >> 16) & 1u)) >> 16);
}
__device__ __forceinline__ float b2f(us h) {
    union { unsigned u; float f; } x; x.u = ((unsigned)h) << 16;
    return x.f;
}

// fragment-major offset (us units) for tile element (d, i, c):
// frag (d*4 + c/32) * 512 + (i + ((c%32)/8)*16) * 8 + c%8
__device__ __forceinline__ int aoff(int d, int i, int c) {
    return ((d * 4 + (c >> 5)) * 64 + (i + (((c >> 3) & 3) << 4))) * 8 + (c & 7);
}

// ---- prep: W[c][o] fp32 -> bf16 hi/lo planes, fragment-major ----
// slot s (0..2047): frag f=s>>6, lane l=s&63 -> o=(f>>2)*16+(l&15),
// c0=(f&3)*32+(l>>4)*8; plane[s*8+j] holds W[c0+j][o].
__global__ void prep_weights(const float* __restrict__ Whz, const float* __restrict__ Wiz,
                             const float* __restrict__ Whr, const float* __restrict__ Wir,
                             const float* __restrict__ Whv, const float* __restrict__ Wiv,
                             const float* __restrict__ Wq,  const float* __restrict__ Wk,
                             us* __restrict__ ws) {
    const int mid = blockIdx.x >> 3;
    const int s = ((blockIdx.x & 7) << 8) + threadIdx.x;
    const float* W; int hp, lp;
    switch (mid) {
        case 0: W = Whz; hp = 0;  lp = -1; break;
        case 1: W = Wiz; hp = 1;  lp = -1; break;
        case 2: W = Whr; hp = 2;  lp = 3;  break;
        case 3: W = Wir; hp = 4;  lp = 5;  break;
        case 4: W = Whv; hp = 6;  lp = 7;  break;
        case 5: W = Wiv; hp = 8;  lp = 9;  break;
        case 6: W = Wq;  hp = 10; lp = -1; break;
        default: W = Wk; hp = 11; lp = 12; break;
    }
    const int f = s >> 6, l = s & 63;
    const int o  = (f >> 2) * 16 + (l & 15);
    const int c0 = (f & 3) * 32 + (l >> 4) * 8;
    us8 hi, lo;
#pragma unroll
    for (int j = 0; j < 8; ++j) {
        float x = W[(c0 + j) * 128 + o];
        us h = f2b(x);
        hi[j] = h;
        lo[j] = f2b(x - b2f(h));
    }
    *(us8*)(ws + hp * PSZ + s * 8) = hi;
    if (lp >= 0) *(us8*)(ws + lp * PSZ + s * 8) = lo;
}

// ---- matmul helpers: A from LDS (fragment-major), B from global planes ----
// zr: zacc += Ah@Pz (plain); racc += Ah@Prh + Al@Prh + Ah@Prl (precise)
__device__ __forceinline__ void mm_zr(const us* __restrict__ Ah, const us* __restrict__ Al,
                                      const us* __restrict__ pz, const us* __restrict__ prh,
                                      const us* __restrict__ prl,
                                      f32x4* zacc, f32x4* racc, int wb, int ab) {
#pragma unroll
    for (int kf = 0; kf < 4; ++kf) {
        bf16x8 bz = *(const bf16x8*)(pz  + wb + kf * 512);
        bf16x8 bh = *(const bf16x8*)(prh + wb + kf * 512);
        bf16x8 bl = *(const bf16x8*)(prl + wb + kf * 512);
#pragma unroll
        for (int m = 0; m < 3; ++m) {
            bf16x8 ah = *(const bf16x8*)(Ah + (m * 4 + kf) * 512 + ab);
            bf16x8 al = *(const bf16x8*)(Al + (m * 4 + kf) * 512 + ab);
            zacc[m] = MFMA(ah, bz, zacc[m], 0, 0, 0);
            racc[m] = MFMA(ah, bh, racc[m], 0, 0, 0);
            racc[m] = MFMA(al, bh, racc[m], 0, 0, 0);
            racc[m] = MFMA(ah, bl, racc[m], 0, 0, 0);
        }
    }
}
// precise: acc += Ah@(Ph+Pl) + Al@Ph
__device__ __forceinline__ void mm_s(const us* __restrict__ Ah, const us* __restrict__ Al,
                                     const us* __restrict__ ph, const us* __restrict__ pl,
                                     f32x4* acc, int wb, int ab) {
#pragma unroll
    for (int kf = 0; kf < 4; ++kf) {
        bf16x8 bh = *(const bf16x8*)(ph + wb + kf * 512);
        bf16x8 bl = *(const bf16x8*)(pl + wb + kf * 512);
#pragma unroll
        for (int m = 0; m < 3; ++m) {
            bf16x8 ah = *(const bf16x8*)(Ah + (m * 4 + kf) * 512 + ab);
            bf16x8 al = *(const bf16x8*)(Al + (m * 4 + kf) * 512 + ab);
            acc[m] = MFMA(ah, bh, acc[m], 0, 0, 0);
            acc[m] = MFMA(al, bh, acc[m], 0, 0, 0);
            acc[m] = MFMA(ah, bl, acc[m], 0, 0, 0);
        }
    }
}
// Q plain, K precise (shared D-frag reads)
__device__ __forceinline__ void mm_qk(const us* __restrict__ Dh, const us* __restrict__ Dl,
                                      const us* __restrict__ pq, const us* __restrict__ pkh,
                                      const us* __restrict__ pkl,
                                      f32x4* qacc, f32x4* kacc, int wb, int ab) {
#pragma unroll
    for (int kf = 0; kf < 4; ++kf) {
        bf16x8 bq = *(const bf16x8*)(pq  + wb + kf * 512);
        bf16x8 bh = *(const bf16x8*)(pkh + wb + kf * 512);
        bf16x8 bl = *(const bf16x8*)(pkl + wb + kf * 512);
#pragma unroll
        for (int m = 0; m < 3; ++m) {
            bf16x8 dh = *(const bf16x8*)(Dh + (m * 4 + kf) * 512 + ab);
            bf16x8 dl = *(const bf16x8*)(Dl + (m * 4 + kf) * 512 + ab);
            qacc[m] = MFMA(dh, bq, qacc[m], 0, 0, 0);
            kacc[m] = MFMA(dh, bh, kacc[m], 0, 0, 0);
            kacc[m] = MFMA(dl, bh, kacc[m], 0, 0, 0);
            kacc[m] = MFMA(dh, bl, kacc[m], 0, 0, 0);
        }
    }
}

__global__ __launch_bounds__(512, 4) void gru_vn_fused(
    const float* __restrict__ v, const float* __restrict__ mv,
    const float* __restrict__ bz, const float* __restrict__ br,
    const us* __restrict__ ws, float* __restrict__ out)
{
    __shared__ __align__(16) us mvh[6144], mvl[6144];   // m_v, later delta
    __shared__ __align__(16) us vth[6144], vtl[6144];   // v, later r*v
    __shared__ __align__(16) float r_t[2048];           // r fp32 [i][c]

    const int tid  = threadIdx.x;
    const int lane = tid & 63;
    const int wave = tid >> 6;
    const int arow = lane & 15;
    const int bo   = wave * 16 + arow;       // output channel
    const int rsub = (lane >> 4) * 4;        // C-frag row offset
    const int ab   = lane * 8;               // A-frag lane offset (us)
    const int wb   = wave * 2048 + lane * 8; // B-frag base (us), +kf*512
    const int n0   = blockIdx.x * NT;

    const us* pWhz  = ws;            const us* pWiz  = ws + 1 * PSZ;
    const us* pWhrh = ws + 2 * PSZ;  const us* pWhrl = ws + 3 * PSZ;
    const us* pWirh = ws + 4 * PSZ;  const us* pWirl = ws + 5 * PSZ;
    const us* pWhvh = ws + 6 * PSZ;  const us* pWhvl = ws + 7 * PSZ;
    const us* pWivh = ws + 8 * PSZ;  const us* pWivl = ws + 9 * PSZ;
    const us* pWq   = ws + 10 * PSZ; const us* pWkh  = ws + 11 * PSZ;
    const us* pWkl  = ws + 12 * PSZ;

    // ---- stage v, m_v (hi/lo) into fragment-major tiles ----
    {
        const float* vs = v  + (size_t)n0 * 384;
        const float* ms = mv + (size_t)n0 * 384;
#pragma unroll
        for (int it = 0; it < 3; ++it) {
            int base = tid * 4 + it * 2048;            // 6144 elems exactly
            float4 a = *(const float4*)(vs + base);
            float4 b = *(const float4*)(ms + base);
            const float* ap = &a.x; const float* bp = &b.x;
#pragma unroll
            for (int j = 0; j < 4; ++j) {
                int idx = base + j;
                int i = idx / 384, rem = idx - i * 384;
                int c = rem / 3, d = rem - c * 3;
                int off = aoff(d, i, c);
                float av = ap[j], bv = bp[j];
                us h;
                h = f2b(av); vth[off] = h; vtl[off] = f2b(av - b2f(h));
                h = f2b(bv); mvh[off] = h; mvl[off] = f2b(bv - b2f(h));
            }
        }
    }
    const float bzv = bz[bo], brv = br[bo];
    const f32x4 Z4 = {0.f, 0.f, 0.f, 0.f};
    __syncthreads();                                   // B1: tiles ready

    // ---- fused z (plain) + r (precise) ----
    f32x4 zacc[3] = {Z4, Z4, Z4}, racc[3] = {Z4, Z4, Z4};
    mm_zr(mvh, mvl, pWhz, pWhrh, pWhrl, zacc, racc, wb, ab);
    mm_zr(vth, vtl, pWiz, pWirh, pWirl, zacc, racc, wb, ab);

    float zz[4], vout[4][3];
#pragma unroll
    for (int q = 0; q < 4; ++q) {
        float h0 = zacc[0][q], h1 = zacc[1][q], h2 = zacc[2][q];
        zz[q] = 1.f / (1.f + __expf(-(sqrtf(h0 * h0 + h1 * h1 + h2 * h2) + bzv)));
        float r0 = racc[0][q], r1 = racc[1][q], r2 = racc[2][q];
        float rr = 1.f / (1.f + __expf(-(sqrtf(r0 * r0 + r1 * r1 + r2 * r2) + brv)));
        r_t[(rsub + q) * 128 + bo] = rr;
        // capture v for final gate before rv overwrites the v tiles
#pragma unroll
        for (int d = 0; d < 3; ++d) {
            int off = aoff(d, rsub + q, bo);
            vout[q][d] = b2f(vth[off]) + b2f(vtl[off]);
        }
    }
    __syncthreads();                                   // B2: r_t visible; v reads done

    // ---- overwrite v tiles with r*v (hi/lo), slot-parallel ----
#pragma unroll
    for (int it = 0; it < 2; ++it) {
        int s = tid + it * 512;
        if (s < 768) {                                 // 768 slots of 8 elems
            int f = s >> 6, l = s & 63;
            int i = l & 15, c0 = (f & 3) * 32 + (l >> 4) * 8;
            us8 vh = *(const us8*)(vth + s * 8);
            us8 vl = *(const us8*)(vtl + s * 8);
            us8 oh, ol;
#pragma unroll
            for (int j = 0; j < 8; ++j) {
                float p = r_t[i * 128 + c0 + j] * (b2f(vh[j]) + b2f(vl[j]));
                us h = f2b(p);
                oh[j] = h; ol[j] = f2b(p - b2f(h));
            }
            *(us8*)(vth + s * 8) = oh;
            *(us8*)(vtl + s * 8) = ol;
        }
    }
    __syncthreads();                                   // B3: rv visible

    // ---- delta = m_v @ Whv + (r*v) @ Wiv (precise) ----
    f32x4 dacc[3] = {Z4, Z4, Z4};
    mm_s(mvh, mvl, pWhvh, pWhvl, dacc, wb, ab);
    mm_s(vth, vtl, pWivh, pWivl, dacc, wb, ab);
    __syncthreads();                                   // B4: mv reads done

    // write delta hi/lo over dead m_v tiles
#pragma unroll
    for (int m = 0; m < 3; ++m)
#pragma unroll
    for (int q = 0; q < 4; ++q) {
        int off = aoff(m, rsub + q, bo);
        float x = dacc[m][q];
        us h = f2b(x);
        mvh[off] = h;
        mvl[off] = f2b(x - b2f(h));
    }
    __syncthreads();                                   // B5: delta visible

    // ---- Q (plain), K (precise) ----
    f32x4 qacc[3] = {Z4, Z4, Z4}, kacc[3] = {Z4, Z4, Z4};
    mm_qk(mvh, mvl, pWq, pWkh, pWkl, qacc, kacc, wb, ab);

    // ---- vn-leaky + gate + store ----
#pragma unroll
    for (int q = 0; q < 4; ++q) {
        const int i = rsub + q;
        float q0 = qacc[0][q], q1 = qacc[1][q], q2 = qacc[2][q];
        float k0 = kacc[0][q], k1 = kacc[1][q], k2 = kacc[2][q];
        float inner = fminf(q0 * k0 + q1 * k1 + q2 * k2, 0.f);
        float kn = sqrtf(k0 * k0 + k1 * k1 + k2 * k2) + 1e-7f;
        float s = inner / (kn * kn);
        float z = zz[q];
        float dv0 = 0.3f * dacc[0][q] + 0.7f * (q0 - s * k0);
        float dv1 = 0.3f * dacc[1][q] + 0.7f * (q1 - s * k1);
        float dv2 = 0.3f * dacc[2][q] + 0.7f * (q2 - s * k2);
        float* op = out + ((size_t)(n0 + i) * 128 + bo) * 3;
        op[0] = (1.f - z) * vout[q][0] + z * dv0;
        op[1] = (1.f - z) * vout[q][1] + z * dv1;
        op[2] = (1.f - z) * vout[q][2] + z * dv2;
    }
}

extern "C" void kernel_launch(void* const* d_in, const int* in_sizes, int n_in,
                              void* d_out, int out_size, void* d_ws, size_t ws_size,
                              hipStream_t stream) {
    (void)in_sizes; (void)n_in; (void)ws_size; (void)out_size;
    us* ws = (us*)d_ws;
    prep_weights<<<64, 256, 0, stream>>>(
        (const float*)d_in[2],  (const float*)d_in[3],
        (const float*)d_in[5],  (const float*)d_in[6],
        (const float*)d_in[8],  (const float*)d_in[9],
        (const float*)d_in[10], (const float*)d_in[11], ws);
    gru_vn_fused<<<NBLK, 512, 0, stream>>>(
        (const float*)d_in[0], (const float*)d_in[1],
        (const float*)d_in[4], (const float*)d_in[7],
        ws, (float*)d_out);
}

// Round 4
// 237.917 us; speedup vs baseline: 6.0469x; 1.1127x over previous
//
#include <hip/hip_runtime.h>

// Fused GRU-vector-neuron cell, MI355X gfx950 — round 4.
// vs round 3 (265us, MfmaUtil 28, VALUBusy 45, 5.9e7 bank conflicts):
//  * Static staging map: thread = (node, channel-quad) -> compile-time c/d
//    decomposition (kills magic-divides), native (__bf16) casts (cvt_pk),
//    ds_write_b64 staging writes (4x fewer, less conflicted).
//  * r_t transposed+padded [c*17+i]: conflict-free r reads/writes.
//  * B-fragments preloaded into register arrays before the preceding barrier
//    (L2 latency hidden under staging/rebuild work).
// Numerics identical to round 3 (absmax 0.031): split-bf16 hi/lo (3 MFMAs)
// on r -> delta -> K; plain bf16 for z and Q.

#define NN   100000
#define NT   16
#define NBLK (NN / NT)   // 6250, exact
#define PSZ  16384       // us per weight plane (128x128 bf16)

typedef unsigned short us;
typedef us     us4    __attribute__((ext_vector_type(4)));
typedef us     us8    __attribute__((ext_vector_type(8)));
typedef __bf16 bf16x8 __attribute__((ext_vector_type(8)));
typedef float  f32x4  __attribute__((ext_vector_type(4)));

#define MFMA __builtin_amdgcn_mfma_f32_16x16x32_bf16

__device__ __forceinline__ us f2b(float f) {   // RNE, used in prep only
    union { float f; unsigned u; } x; x.f = f;
    return (us)((x.u + 0x7FFFu + ((x.u >> 16) & 1u)) >> 16);
}
__device__ __forceinline__ float b2f(us h) {
    union { unsigned u; float f; } x; x.u = ((unsigned)h) << 16;
    return x.f;
}

// ---- prep: W[c][o] fp32 -> bf16 hi/lo planes, fragment-major (as round 3) ----
__global__ void prep_weights(const float* __restrict__ Whz, const float* __restrict__ Wiz,
                             const float* __restrict__ Whr, const float* __restrict__ Wir,
                             const float* __restrict__ Whv, const float* __restrict__ Wiv,
                             const float* __restrict__ Wq,  const float* __restrict__ Wk,
                             us* __restrict__ ws) {
    const int mid = blockIdx.x >> 3;
    const int s = ((blockIdx.x & 7) << 8) + threadIdx.x;
    const float* W; int hp, lp;
    switch (mid) {
        case 0: W = Whz; hp = 0;  lp = -1; break;
        case 1: W = Wiz; hp = 1;  lp = -1; break;
        case 2: W = Whr; hp = 2;  lp = 3;  break;
        case 3: W = Wir; hp = 4;  lp = 5;  break;
        case 4: W = Whv; hp = 6;  lp = 7;  break;
        case 5: W = Wiv; hp = 8;  lp = 9;  break;
        case 6: W = Wq;  hp = 10; lp = -1; break;
        default: W = Wk; hp = 11; lp = 12; break;
    }
    const int f = s >> 6, l = s & 63;
    const int o  = (f >> 2) * 16 + (l & 15);
    const int c0 = (f & 3) * 32 + (l >> 4) * 8;
    us8 hi, lo;
#pragma unroll
    for (int j = 0; j < 8; ++j) {
        float x = W[(c0 + j) * 128 + o];
        us h = f2b(x);
        hi[j] = h;
        lo[j] = f2b(x - b2f(h));
    }
    *(us8*)(ws + hp * PSZ + s * 8) = hi;
    if (lp >= 0) *(us8*)(ws + lp * PSZ + s * 8) = lo;
}

// ---- B-fragment register preload: 4 kf x bf16x8 from a plane ----
__device__ __forceinline__ void loadB4(const us* __restrict__ p, int wb, bf16x8* d) {
#pragma unroll
    for (int kf = 0; kf < 4; ++kf) d[kf] = *(const bf16x8*)(p + wb + kf * 512);
}

// zacc += Ah@Bz (plain); racc += Ah@Bh + Al@Bh + Ah@Bl (precise)
__device__ __forceinline__ void mm_zr(const us* __restrict__ Ah, const us* __restrict__ Al,
                                      const bf16x8* bz, const bf16x8* bh, const bf16x8* bl,
                                      f32x4* zacc, f32x4* racc, int ab) {
#pragma unroll
    for (int kf = 0; kf < 4; ++kf)
#pragma unroll
        for (int m = 0; m < 3; ++m) {
            bf16x8 ah = *(const bf16x8*)(Ah + (m * 4 + kf) * 512 + ab);
            bf16x8 al = *(const bf16x8*)(Al + (m * 4 + kf) * 512 + ab);
            zacc[m] = MFMA(ah, bz[kf], zacc[m], 0, 0, 0);
            racc[m] = MFMA(ah, bh[kf], racc[m], 0, 0, 0);
            racc[m] = MFMA(al, bh[kf], racc[m], 0, 0, 0);
            racc[m] = MFMA(ah, bl[kf], racc[m], 0, 0, 0);
        }
}
// acc += Ah@(Bh+Bl) + Al@Bh
__device__ __forceinline__ void mm_s(const us* __restrict__ Ah, const us* __restrict__ Al,
                                     const bf16x8* bh, const bf16x8* bl,
                                     f32x4* acc, int ab) {
#pragma unroll
    for (int kf = 0; kf < 4; ++kf)
#pragma unroll
        for (int m = 0; m < 3; ++m) {
            bf16x8 ah = *(const bf16x8*)(Ah + (m * 4 + kf) * 512 + ab);
            bf16x8 al = *(const bf16x8*)(Al + (m * 4 + kf) * 512 + ab);
            acc[m] = MFMA(ah, bh[kf], acc[m], 0, 0, 0);
            acc[m] = MFMA(al, bh[kf], acc[m], 0, 0, 0);
            acc[m] = MFMA(ah, bl[kf], acc[m], 0, 0, 0);
        }
}
// Q plain, K precise (shared D-frag reads)
__device__ __forceinline__ void mm_qk(const us* __restrict__ Dh, const us* __restrict__ Dl,
                                      const bf16x8* bq, const bf16x8* bh, const bf16x8* bl,
                                      f32x4* qacc, f32x4* kacc, int ab) {
#pragma unroll
    for (int kf = 0; kf < 4; ++kf)
#pragma unroll
        for (int m = 0; m < 3; ++m) {
            bf16x8 dh = *(const bf16x8*)(Dh + (m * 4 + kf) * 512 + ab);
            bf16x8 dl = *(const bf16x8*)(Dl + (m * 4 + kf) * 512 + ab);
            qacc[m] = MFMA(dh, bq[kf], qacc[m], 0, 0, 0);
            kacc[m] = MFMA(dh, bh[kf], kacc[m], 0, 0, 0);
            kacc[m] = MFMA(dl, bh[kf], kacc[m], 0, 0, 0);
            kacc[m] = MFMA(dh, bl[kf], kacc[m], 0, 0, 0);
        }
}

__global__ __launch_bounds__(512, 4) void gru_vn_fused(
    const float* __restrict__ v, const float* __restrict__ mv,
    const float* __restrict__ bz, const float* __restrict__ br,
    const us* __restrict__ ws, float* __restrict__ out)
{
    __shared__ __align__(16) us mvh[6144], mvl[6144];   // m_v, later delta
    __shared__ __align__(16) us vth[6144], vtl[6144];   // v, later r*v
    __shared__ __align__(16) float r_t[128 * 17];       // r fp32, [c*17 + i]

    const int tid  = threadIdx.x;
    const int lane = tid & 63;
    const int wave = tid >> 6;
    const int arow = lane & 15;
    const int bo   = wave * 16 + arow;       // output channel
    const int rsub = (lane >> 4) * 4;        // C-frag row offset
    const int ab   = lane * 8;               // A-frag lane offset (us)
    const int wb   = wave * 2048 + lane * 8; // B-frag base (us), +kf*512
    const int n0   = blockIdx.x * NT;

    const us* pWhz  = ws;            const us* pWiz  = ws + 1 * PSZ;
    const us* pWhrh = ws + 2 * PSZ;  const us* pWhrl = ws + 3 * PSZ;
    const us* pWirh = ws + 4 * PSZ;  const us* pWirl = ws + 5 * PSZ;
    const us* pWhvh = ws + 6 * PSZ;  const us* pWhvl = ws + 7 * PSZ;
    const us* pWivh = ws + 8 * PSZ;  const us* pWivl = ws + 9 * PSZ;
    const us* pWq   = ws + 10 * PSZ; const us* pWkh  = ws + 11 * PSZ;
    const us* pWkl  = ws + 12 * PSZ;

    // ---- stage v, m_v (hi/lo): thread = (node ind, channel-quad q4) ----
    {
        const int ind = tid >> 5;            // node 0..15
        const int q4  = tid & 31;            // channel quad
        const int c0s = q4 * 4;              // c0 ≡ 0 or 4 (mod 8)
        const float* vp = v  + (size_t)(n0 + ind) * 384 + q4 * 12;
        const float* mp = mv + (size_t)(n0 + ind) * 384 + q4 * 12;
        float xv[12], xm[12];
        *(float4*)(xv + 0) = *(const float4*)(vp + 0);
        *(float4*)(xv + 4) = *(const float4*)(vp + 4);
        *(float4*)(xv + 8) = *(const float4*)(vp + 8);
        *(float4*)(xm + 0) = *(const float4*)(mp + 0);
        *(float4*)(xm + 4) = *(const float4*)(mp + 4);
        *(float4*)(xm + 8) = *(const float4*)(mp + 8);
        // aoff(d, ind, c0s) = sb + d*2048; 4 channels stay inside one 8-slot
        const int sb = ((c0s >> 5) * 64 + ind + (((c0s >> 3) & 3) << 4)) * 8 + (c0s & 7);
#pragma unroll
        for (int d = 0; d < 3; ++d) {
            us4 vh4, vl4, mh4, ml4;
#pragma unroll
            for (int e = 0; e < 4; ++e) {
                float x = xv[d + e * 3];
                __bf16 h = (__bf16)x;
                vh4[e] = __builtin_bit_cast(us, h);
                vl4[e] = __builtin_bit_cast(us, (__bf16)(x - (float)h));
                x = xm[d + e * 3];
                h = (__bf16)x;
                mh4[e] = __builtin_bit_cast(us, h);
                ml4[e] = __builtin_bit_cast(us, (__bf16)(x - (float)h));
            }
            *(us4*)(vth + sb + d * 2048) = vh4;
            *(us4*)(vtl + sb + d * 2048) = vl4;
            *(us4*)(mvh + sb + d * 2048) = mh4;
            *(us4*)(mvl + sb + d * 2048) = ml4;
        }
    }
    const float bzv = bz[bo], brv = br[bo];
    const f32x4 Z4 = {0.f, 0.f, 0.f, 0.f};

    // preload phase-1 B-frags before the barrier (global, no LDS dep)
    bf16x8 Bz[4], Brh[4], Brl[4];
    loadB4(pWhz, wb, Bz); loadB4(pWhrh, wb, Brh); loadB4(pWhrl, wb, Brl);
    __syncthreads();                                   // B1: tiles ready

    // ---- fused z (plain) + r (precise) ----
    f32x4 zacc[3] = {Z4, Z4, Z4}, racc[3] = {Z4, Z4, Z4};
    mm_zr(mvh, mvl, Bz, Brh, Brl, zacc, racc, ab);
    loadB4(pWiz, wb, Bz); loadB4(pWirh, wb, Brh); loadB4(pWirl, wb, Brl);
    mm_zr(vth, vtl, Bz, Brh, Brl, zacc, racc, ab);

    const int vbase = ((bo >> 5) * 64 + rsub + (((bo >> 3) & 3) << 4)) * 8 + (bo & 7);
    float zz[4], vout[4][3];
#pragma unroll
    for (int q = 0; q < 4; ++q) {
        float h0 = zacc[0][q], h1 = zacc[1][q], h2 = zacc[2][q];
        zz[q] = 1.f / (1.f + __expf(-(sqrtf(h0 * h0 + h1 * h1 + h2 * h2) + bzv)));
        float r0 = racc[0][q], r1 = racc[1][q], r2 = racc[2][q];
        float rr = 1.f / (1.f + __expf(-(sqrtf(r0 * r0 + r1 * r1 + r2 * r2) + brv)));
        r_t[bo * 17 + rsub + q] = rr;
#pragma unroll
        for (int d = 0; d < 3; ++d) {
            int off = vbase + d * 2048 + q * 8;
            vout[q][d] = b2f(vth[off]) + b2f(vtl[off]);
        }
    }
    // preload delta-phase B (Whv) before rebuild barrier
    bf16x8 Bdh[4], Bdl[4];
    loadB4(pWhvh, wb, Bdh); loadB4(pWhvl, wb, Bdl);
    __syncthreads();                                   // B2: r_t visible; v reads done

    // ---- overwrite v tiles with r*v (hi/lo), slot-parallel us8 ----
#pragma unroll
    for (int it = 0; it < 2; ++it) {
        int s = tid + it * 512;
        if (s < 768) {                                 // 768 slots, wave-uniform guard
            int f = s >> 6, l = s & 63;
            int i = l & 15, cb = (f & 3) * 32 + (l >> 4) * 8;
            us8 vh8 = *(const us8*)(vth + s * 8);
            us8 vl8 = *(const us8*)(vtl + s * 8);
            us8 oh, ol;
#pragma unroll
            for (int j = 0; j < 8; ++j) {
                float p = r_t[(cb + j) * 17 + i] * (b2f(vh8[j]) + b2f(vl8[j]));
                __bf16 h = (__bf16)p;
                oh[j] = __builtin_bit_cast(us, h);
                ol[j] = __builtin_bit_cast(us, (__bf16)(p - (float)h));
            }
            *(us8*)(vth + s * 8) = oh;
            *(us8*)(vtl + s * 8) = ol;
        }
    }
    __syncthreads();                                   // B3: rv visible

    // ---- delta = m_v @ Whv + (r*v) @ Wiv (precise) ----
    f32x4 dacc[3] = {Z4, Z4, Z4};
    mm_s(mvh, mvl, Bdh, Bdl, dacc, ab);
    loadB4(pWivh, wb, Bdh); loadB4(pWivl, wb, Bdl);
    mm_s(vth, vtl, Bdh, Bdl, dacc, ab);
    __syncthreads();                                   // B4: mv reads done

    // write delta hi/lo over dead m_v tiles
#pragma unroll
    for (int m = 0; m < 3; ++m)
#pragma unroll
    for (int q = 0; q < 4; ++q) {
        int off = vbase + m * 2048 + q * 8;
        float x = dacc[m][q];
        __bf16 h = (__bf16)x;
        mvh[off] = __builtin_bit_cast(us, h);
        mvl[off] = __builtin_bit_cast(us, (__bf16)(x - (float)h));
    }
    // preload QK-phase B before the barrier
    bf16x8 Bq[4], Bkh[4], Bkl[4];
    loadB4(pWq, wb, Bq); loadB4(pWkh, wb, Bkh); loadB4(pWkl, wb, Bkl);
    __syncthreads();                                   // B5: delta visible

    // ---- Q (plain), K (precise) ----
    f32x4 qacc[3] = {Z4, Z4, Z4}, kacc[3] = {Z4, Z4, Z4};
    mm_qk(mvh, mvl, Bq, Bkh, Bkl, qacc, kacc, ab);

    // ---- vn-leaky + gate + store ----
#pragma unroll
    for (int q = 0; q < 4; ++q) {
        const int i = rsub + q;
        float q0 = qacc[0][q], q1 = qacc[1][q], q2 = qacc[2][q];
        float k0 = kacc[0][q], k1 = kacc[1][q], k2 = kacc[2][q];
        float inner = fminf(q0 * k0 + q1 * k1 + q2 * k2, 0.f);
        float kn = sqrtf(k0 * k0 + k1 * k1 + k2 * k2) + 1e-7f;
        float s = inner / (kn * kn);
        float z = zz[q];
        float dv0 = 0.3f * dacc[0][q] + 0.7f * (q0 - s * k0);
        float dv1 = 0.3f * dacc[1][q] + 0.7f * (q1 - s * k1);
        float dv2 = 0.3f * dacc[2][q] + 0.7f * (q2 - s * k2);
        float* op = out + ((size_t)(n0 + i) * 128 + bo) * 3;
        op[0] = (1.f - z) * vout[q][0] + z * dv0;
        op[1] = (1.f - z) * vout[q][1] + z * dv1;
        op[2] = (1.f - z) * vout[q][2] + z * dv2;
    }
}

extern "C" void kernel_launch(void* const* d_in, const int* in_sizes, int n_in,
                              void* d_out, int out_size, void* d_ws, size_t ws_size,
                              hipStream_t stream) {
    (void)in_sizes; (void)n_in; (void)ws_size; (void)out_size;
    us* ws = (us*)d_ws;
    prep_weights<<<64, 256, 0, stream>>>(
        (const float*)d_in[2],  (const float*)d_in[3],
        (const float*)d_in[5],  (const float*)d_in[6],
        (const float*)d_in[8],  (const float*)d_in[9],
        (const float*)d_in[10], (const float*)d_in[11], ws);
    gru_vn_fused<<<NBLK, 512, 0, stream>>>(
        (const float*)d_in[0], (const float*)d_in[1],
        (const float*)d_in[4], (const float*)d_in[7],
        ws, (float*)d_out);
}